// Round 4
// baseline (257.336 us; speedup 1.0000x reference)
//
#include <hip/hip_runtime.h>

using u16 = unsigned short;
using u32 = unsigned int;

typedef __bf16 bf16x8 __attribute__((ext_vector_type(8)));
typedef float  f32x4  __attribute__((ext_vector_type(4)));

#define NPOS   225          // 15*15 valid positions
#define NT     15           // row-tiles; p' = i*16 + j (j<15 valid)
#define A_ROWS 289          // 17*17 haloed, ROWP=128 u16 (256B row, swizzled)
#define B_ROWS 240          // compact p' rows
#define A_ELEMS (A_ROWS*128)             // 36992 u16
#define B_ELEMS (B_ROWS*128)             // 30720 u16
#define LDS_BYTES ((A_ELEMS + B_ELEMS)*2)  // 135424 B < 160 KiB

// ---- workspace layout ----
// floats [0..768): dconv0 weights transposed [k=c*3+t][o]
// then bf16 (u16) region, offsets in u16 units:
#define WA_PER_L 49152      // per dconv layer: [8 ot][12 f=t*4+kb][64 lane][8]
#define WP_OFF   (4*WA_PER_L)          // 196608 ; 6 x [8 ot][4 kb][64][8]
#define WP_PER   16384
#define WF_OFF   (WP_OFF + 6*WP_PER)   // 294912 ; [4 ot][4 kb][64][8]
#define W_U16_TOTAL (WF_OFF + 8192)    // 303104

__device__ __forceinline__ float bflo(u32 q){ return __uint_as_float(q << 16); }
__device__ __forceinline__ float bfhi(u32 q){ return __uint_as_float(q & 0xffff0000u); }
__device__ __forceinline__ u16 f2bf(float f){
  u32 u = __float_as_uint(f);
  return (u16)((u + 0x7fffu + ((u >> 16) & 1u)) >> 16);   // RNE (prep kernel only)
}
__device__ __forceinline__ u32 packbf(float a, float b){
  union { __bf16 h[2]; u32 u; } r;
  r.h[0] = (__bf16)a; r.h[1] = (__bf16)b;   // native cast -> v_cvt_pk_bf16_f32
  return r.u;
}
__device__ __forceinline__ float silu_f(float x){
  return x * __builtin_amdgcn_rcpf(1.f + __expf(-x));
}
__device__ __forceinline__ f32x4 mfma16(bf16x8 a, bf16x8 b, f32x4 c){
  return __builtin_amdgcn_mfma_f32_16x16x32_bf16(a, b, c, 0, 0, 0);
}

// ---- weight prep: fp32 transpose for dconv0 + bf16 per-lane fragment swizzle ----
__global__ void prep_w(const float* __restrict__ d0w, const float* __restrict__ rdw,
                       const float* __restrict__ rpw, const float* __restrict__ c1w,
                       const float* __restrict__ c2w, const float* __restrict__ fw,
                       float* __restrict__ ws)
{
  u16* wsb = (u16*)(ws + 768);
  const int total = 768 + W_U16_TOTAL;
  for (int idx = blockIdx.x*blockDim.x + threadIdx.x; idx < total; idx += gridDim.x*blockDim.x){
    if (idx < 768){                      // dconv0 fp32: [6][128] <- [128][2][3]
      int k = idx >> 7, o = idx & 127;
      ws[idx] = d0w[o*6 + k];
      continue;
    }
    int e = idx - 768;
    float v;
    if (e < WP_OFF){                     // res dconv frags
      int L = e / WA_PER_L, r = e % WA_PER_L;
      int w = r / 6144, r2 = r % 6144;
      int t = r2 >> 11, r3 = r2 & 2047;  // t stride 2048
      int kb = r3 >> 9, r4 = r3 & 511;
      int l = r4 >> 3, j = r4 & 7;
      int o = w*16 + (l & 15);
      int c = kb*32 + ((l >> 4) << 3) + j;
      v = rdw[((L*128 + o)*128 + c)*3 + t];
    } else if (e < WF_OFF){              // pointwise frags (res0..3, c1, c2)
      int t2 = e - WP_OFF;
      int i = t2 / WP_PER, r = t2 % WP_PER;
      int w = r >> 11, r2 = r & 2047;
      int kb = r2 >> 9, r3 = r2 & 511;
      int l = r3 >> 3, j = r3 & 7;
      int o = w*16 + (l & 15);
      int c = kb*32 + ((l >> 4) << 3) + j;
      v = (i < 4) ? rpw[(i*128 + o)*128 + c]
        : (i == 4) ? c1w[o*128 + c] : c2w[o*128 + c];
    } else {                             // final frags
      int e2 = e - WF_OFF;
      int ot = e2 >> 11, r = e2 & 2047;
      int kb = r >> 9, r2 = r & 511;
      int l = r2 >> 3, j = r2 & 7;
      int o = ot*16 + (l & 15);
      int c = kb*32 + ((l >> 4) << 3) + j;
      v = fw[o*128 + c];
    }
    wsb[e] = f2bf(v);
  }
}

// ---- directional conv 128->128 via MFMA: A(haloed,swz) -> B(compact,swz) ----
// wave owns o-tiles {2og, 2og+1} (32 ch) and row-tiles [T0,T1)
__device__ __forceinline__ void dconv_mfma(const u16* __restrict__ As, u16* __restrict__ Bs,
    const u16* __restrict__ wloc, const float* __restrict__ bias,
    int lane, int og, int T0, int T1, int dr0, int dr2)
{
  const int col = lane & 15, kg = lane >> 4;
  const int k0 = kg*8;
  bf16x8 wa[2][12];
  #pragma unroll
  for (int ot=0; ot<2; ++ot)
    #pragma unroll
    for (int f=0; f<12; ++f)
      wa[ot][f] = *(const bf16x8*)(wloc + (2*og+ot)*6144 + f*512 + lane*8);
  f32x4 bz0 = *(const f32x4*)(bias + (2*og)*16 + kg*4);
  f32x4 bz1 = *(const f32x4*)(bias + (2*og+1)*16 + kg*4);
  const int chb = og*32 + kg*4;
  int r1 = (T0+1)*17 + col + 1;
  int p2 = T0*16 + col;
  #pragma unroll 1
  for (int tile=T0; tile<T1; ++tile){
    int ra = r1 + dr0, rc = r1 + dr2;
    int sa = (ra&15)<<3, sb = (r1&15)<<3, sc = (rc&15)<<3;
    const u16* A0 = As + (ra<<7);
    const u16* A1 = As + (r1<<7);
    const u16* A2 = As + (rc<<7);
    f32x4 a0 = bz0, a1 = bz1;
    __builtin_amdgcn_s_setprio(1);
    #pragma unroll
    for (int kb=0; kb<4; ++kb){
      const int kk = k0 + kb*32;
      bf16x8 v0 = *(const bf16x8*)(A0 + (kk ^ sa));
      bf16x8 v1 = *(const bf16x8*)(A1 + (kk ^ sb));
      bf16x8 v2 = *(const bf16x8*)(A2 + (kk ^ sc));
      a0 = mfma16(wa[0][kb],   v0, a0); a1 = mfma16(wa[1][kb],   v0, a1);
      a0 = mfma16(wa[0][4+kb], v1, a0); a1 = mfma16(wa[1][4+kb], v1, a1);
      a0 = mfma16(wa[0][8+kb], v2, a0); a1 = mfma16(wa[1][8+kb], v2, a1);
    }
    __builtin_amdgcn_s_setprio(0);
    if (col < 15){
      int idx = (p2<<7) + (chb ^ ((p2&15)<<3));
      uint2 w0; w0.x = packbf(silu_f(a0[0]), silu_f(a0[1]));
      w0.y = packbf(silu_f(a0[2]), silu_f(a0[3]));
      *(uint2*)(Bs + idx) = w0;
      uint2 w1; w1.x = packbf(silu_f(a1[0]), silu_f(a1[1]));
      w1.y = packbf(silu_f(a1[2]), silu_f(a1[3]));
      *(uint2*)(Bs + (idx ^ 16)) = w1;
    }
    r1 += 17; p2 += 16;
  }
}

// ---- pointwise 128->128 via MFMA; wave owns 4 o-tiles (64 ch), tiles [T0,T1) ----
template<bool SRC_HALO, bool DST_HALO, bool RESID>
__device__ __forceinline__ void pw_mfma(const u16* __restrict__ src, u16* __restrict__ dst,
    const u16* __restrict__ wloc, const float* __restrict__ bias,
    int lane, int og2, int T0, int T1)
{
  const int col = lane & 15, kg = lane >> 4;
  const int k0 = kg*8;
  bf16x8 wp[4][4];
  #pragma unroll
  for (int ot=0; ot<4; ++ot)
    #pragma unroll
    for (int kb=0; kb<4; ++kb)
      wp[ot][kb] = *(const bf16x8*)(wloc + (og2*4+ot)*2048 + kb*512 + lane*8);
  f32x4 bz[4];
  #pragma unroll
  for (int ot=0; ot<4; ++ot) bz[ot] = *(const f32x4*)(bias + og2*64 + ot*16 + kg*4);
  const int chb = og2*64 + kg*4;
  int r1 = (T0+1)*17 + col + 1;
  int p2 = T0*16 + col;
  #pragma unroll 2
  for (int tile=T0; tile<T1; ++tile){
    int rs = SRC_HALO ? r1 : p2;
    const u16* S = src + (rs<<7);
    int ss = (rs&15)<<3;
    f32x4 a0 = bz[0], a1 = bz[1], a2 = bz[2], a3 = bz[3];
    __builtin_amdgcn_s_setprio(1);
    #pragma unroll
    for (int kb=0; kb<4; ++kb){
      bf16x8 v = *(const bf16x8*)(S + ((k0 + kb*32) ^ ss));
      a0 = mfma16(wp[0][kb], v, a0);
      a1 = mfma16(wp[1][kb], v, a1);
      a2 = mfma16(wp[2][kb], v, a2);
      a3 = mfma16(wp[3][kb], v, a3);
    }
    __builtin_amdgcn_s_setprio(0);
    if (col < 15){
      int rd = DST_HALO ? r1 : p2;
      int idx0 = (rd<<7) + (chb ^ ((rd&15)<<3));
      f32x4 aa[4] = {a0, a1, a2, a3};
      #pragma unroll
      for (int ot=0; ot<4; ++ot){
        int idx = idx0 ^ (ot<<4);
        float s0 = silu_f(aa[ot][0]), s1 = silu_f(aa[ot][1]);
        float s2 = silu_f(aa[ot][2]), s3 = silu_f(aa[ot][3]);
        if (RESID){
          uint2 r = *(const uint2*)(dst + idx);
          s0 += bflo(r.x); s1 += bfhi(r.x); s2 += bflo(r.y); s3 += bfhi(r.y);
        }
        uint2 w0; w0.x = packbf(s0, s1); w0.y = packbf(s2, s3);
        *(uint2*)(dst + idx) = w0;
      }
    }
    r1 += 17; p2 += 16;
  }
}

__global__ void __launch_bounds__(512, 2)
mix9_main(const float* __restrict__ x,
          const float* __restrict__ b_d0,
          const float* __restrict__ b_rd,
          const float* __restrict__ b_rp,
          const float* __restrict__ b_c1,
          const float* __restrict__ b_c2,
          const float* __restrict__ b_fin,
          const float* __restrict__ wt,
          float* __restrict__ out)
{
  extern __shared__ u16 sm[];
  u16* As = sm;              // [289][128] haloed bf16, XOR-swizzled, zero halo
  u16* Bs = sm + A_ELEMS;    // [240][128] compact p'-row scratch, swizzled

  const int blk  = blockIdx.x;
  const int b    = blk >> 2, d = blk & 3;
  const int tid  = threadIdx.x;
  const int wave = __builtin_amdgcn_readfirstlane(tid >> 6);
  const int lane = tid & 63;
  const int og   = wave >> 1;        // dconv/final: o-tiles {2og,2og+1}
  const int ph   = wave & 1;
  const int T0   = ph * 8;
  const int T1   = ph ? NT : 8;
  const int og2  = wave >> 2;        // pw: o-tiles [4*og2, 4*og2+4)
  const int ph4  = wave & 3;
  const int T0p  = ph4 * 4;
  const int T1p  = (ph4 == 3) ? NT : T0p + 4;
  const int ob   = wave * 16;        // dconv0 prologue channel base

  const int DI0[4] = {0,-1, 1,-1}, DJ0[4] = {-1, 0,-1,-1};
  const int DI2[4] = {0, 1,-1, 1}, DJ2[4] = { 1, 0, 1, 1};
  const int di0 = DI0[d], dj0 = DJ0[d], di2 = DI2[d], dj2 = DJ2[d];
  const int dr0 = di0*17 + dj0;      // tap row-index deltas in the 17x17 halo grid
  const int dr2 = di2*17 + dj2;

  // zero haloed A; stage input image into B-region as fp32
  for (int k2 = tid; k2 < A_ELEMS; k2 += 512) As[k2] = 0;
  float* xs = (float*)Bs;          // 450 floats
  for (int k2 = tid; k2 < 2*NPOS; k2 += 512) xs[k2] = x[b*(2*NPOS) + k2];
  __syncthreads();

  // ---- dconv0: 2 -> 128 (tiny K: plain VALU, fp32 weights) -> A (swizzled) ----
  #pragma unroll 1
  for (int pb = 0; pb < 4; ++pb){
    int pp = pb*64 + lane;           // p' = i*16 + j
    int i = pp >> 4, j = pp & 15;
    if (i >= 15 || j >= 15) continue;
    float acc[16];
    #pragma unroll
    for (int oo=0;oo<16;++oo) acc[oo] = b_d0[ob+oo];
    #pragma unroll
    for (int c=0;c<2;++c){
      int i0=i+di0, j0=j+dj0, i2=i+di2, j2=j+dj2;
      float x0 = ((unsigned)i0<15u && (unsigned)j0<15u) ? xs[c*NPOS + i0*15 + j0] : 0.f;
      float x1 = xs[c*NPOS + i*15 + j];
      float x2 = ((unsigned)i2<15u && (unsigned)j2<15u) ? xs[c*NPOS + i2*15 + j2] : 0.f;
      const float* w0r = wt + (c*3+0)*128 + ob;
      const float* w1r = wt + (c*3+1)*128 + ob;
      const float* w2r = wt + (c*3+2)*128 + ob;
      #pragma unroll
      for (int oo=0;oo<16;++oo)
        acc[oo] = fmaf(w0r[oo],x0, fmaf(w1r[oo],x1, fmaf(w2r[oo],x2, acc[oo])));
    }
    int r = (i+1)*17 + (j+1);
    int s = (r&15)<<3;
    u16* rowp = As + (r<<7);
    #pragma unroll
    for (int oo=0;oo<16;oo+=2)
      *(u32*)(rowp + ((ob+oo) ^ s)) = packbf(silu_f(acc[oo]), silu_f(acc[oo+1]));
  }
  __syncthreads();

  const u16* wsb = (const u16*)(wt + 768);

  // ---- 4 directional res blocks (MFMA) ----
  #pragma unroll 1
  for (int L = 0; L < 4; ++L){
    dconv_mfma(As, Bs, wsb + L*WA_PER_L, b_rd + L*128, lane, og, T0, T1, dr0, dr2);
    __syncthreads();
    pw_mfma<false,true,true>(Bs, As, wsb + WP_OFF + L*WP_PER, b_rp + L*128, lane, og2, T0p, T1p);
    __syncthreads();
  }

  // ---- Conv0d res block ----
  pw_mfma<true,false,false>(As, Bs, wsb + WP_OFF + 4*WP_PER, b_c1, lane, og2, T0p, T1p);
  __syncthreads();
  pw_mfma<false,true,true>(Bs, As, wsb + WP_OFF + 5*WP_PER, b_c2, lane, og2, T0p, T1p);
  __syncthreads();

  // ---- final 1x1: 128 -> 64, MFMA, write global fp32 ----
  {
    const int col = lane & 15, kg = lane >> 4;
    const int k0 = kg*8;
    const u16* wl = wsb + WF_OFF + og*2048;
    bf16x8 wf[4];
    #pragma unroll
    for (int kb=0;kb<4;++kb) wf[kb] = *(const bf16x8*)(wl + (kb*64 + lane)*8);
    f32x4 bias4 = *(const f32x4*)(b_fin + og*16 + kg*4);
    int r1 = (T0+1)*17 + col + 1;
    #pragma unroll 1
    for (int tile = T0; tile < T1; ++tile){
      const u16* S = As + (r1<<7);
      int ss = (r1&15)<<3;
      f32x4 acc = bias4;
      #pragma unroll
      for (int kb=0;kb<4;++kb)
        acc = mfma16(wf[kb], *(const bf16x8*)(S + ((k0 + kb*32) ^ ss)), acc);
      if (col < 15){
        float* op = out + ((size_t)((b*4 + d)*64 + og*16 + kg*4))*NPOS + tile*15 + col;
        op[0]      = acc[0];
        op[NPOS]   = acc[1];
        op[2*NPOS] = acc[2];
        op[3*NPOS] = acc[3];
      }
      r1 += 17;
    }
  }
}

extern "C" void kernel_launch(void* const* d_in, const int* in_sizes, int n_in,
                              void* d_out, int out_size, void* d_ws, size_t ws_size,
                              hipStream_t stream)
{
  const float* x     = (const float*)d_in[0];
  const float* w_d0  = (const float*)d_in[1];
  const float* b_d0  = (const float*)d_in[2];
  const float* w_rd  = (const float*)d_in[3];
  const float* b_rd  = (const float*)d_in[4];
  const float* w_rp  = (const float*)d_in[5];
  const float* b_rp  = (const float*)d_in[6];
  const float* w_c1  = (const float*)d_in[7];
  const float* b_c1  = (const float*)d_in[8];
  const float* w_c2  = (const float*)d_in[9];
  const float* b_c2  = (const float*)d_in[10];
  const float* w_fin = (const float*)d_in[11];
  const float* b_fin = (const float*)d_in[12];
  float* wt  = (float*)d_ws;
  float* out = (float*)d_out;

  prep_w<<<128, 512, 0, stream>>>(w_d0, w_rd, w_rp, w_c1, w_c2, w_fin, wt);

  (void)hipFuncSetAttribute((const void*)mix9_main,
                            hipFuncAttributeMaxDynamicSharedMemorySize, LDS_BYTES);
  mix9_main<<<1024, 512, LDS_BYTES, stream>>>(x, b_d0, b_rd, b_rp, b_c1, b_c2, b_fin, wt, out);
}

// Round 5
// 244.288 us; speedup vs baseline: 1.0534x; 1.0534x over previous
//
#include <hip/hip_runtime.h>

using u16 = unsigned short;
using u32 = unsigned int;

typedef __bf16 bf16x8 __attribute__((ext_vector_type(8)));
typedef float  f32x4  __attribute__((ext_vector_type(4)));

#define NPOS   225          // 15*15 valid positions
#define NT     15           // row-tiles; p' = i*16 + j (j<15 valid)
#define ROWP   136          // padded LDS row stride in ushorts (272B, 16B-aligned)
#define A_ROWS 289          // 17*17 haloed
#define B_ROWS 241          // 240 p' rows + 1 guard
#define A_ELEMS (A_ROWS*ROWP)            // 39304 u16
#define B_ELEMS (B_ROWS*ROWP)            // 32776 u16
#define LDS_BYTES ((A_ELEMS + B_ELEMS)*2)  // 144160 B < 160 KiB
#define RSTRIDE17 (17*ROWP)              // 2312

// ---- workspace layout ----
// floats [0..768): dconv0 weights transposed [k=c*3+t][o]
// then bf16 (u16) region, offsets in u16 units:
#define WA_PER_L 49152      // per dconv layer: [8 ot][12 f=t*4+kb][64 lane][8]
#define WP_OFF   (4*WA_PER_L)          // 196608 ; 6 x [8 ot][4 kb][64][8]
#define WP_PER   16384
#define WF_OFF   (WP_OFF + 6*WP_PER)   // 294912 ; [4 ot][4 kb][64][8]
#define W_U16_TOTAL (WF_OFF + 8192)    // 303104

__device__ __forceinline__ float bflo(u32 q){ return __uint_as_float(q << 16); }
__device__ __forceinline__ float bfhi(u32 q){ return __uint_as_float(q & 0xffff0000u); }
__device__ __forceinline__ u16 f2bf(float f){
  u32 u = __float_as_uint(f);
  return (u16)((u + 0x7fffu + ((u >> 16) & 1u)) >> 16);   // RNE (prep kernel only)
}
__device__ __forceinline__ u32 packbf(float a, float b){
  union { __bf16 h[2]; u32 u; } r;
  r.h[0] = (__bf16)a; r.h[1] = (__bf16)b;   // native cast -> v_cvt_pk_bf16_f32
  return r.u;
}
__device__ __forceinline__ float silu_f(float x){
  return x * __builtin_amdgcn_rcpf(1.f + __expf(-x));
}
__device__ __forceinline__ f32x4 mfma16(bf16x8 a, bf16x8 b, f32x4 c){
  return __builtin_amdgcn_mfma_f32_16x16x32_bf16(a, b, c, 0, 0, 0);
}

// ---- weight prep: fp32 transpose for dconv0 + bf16 per-lane fragment swizzle ----
__global__ void prep_w(const float* __restrict__ d0w, const float* __restrict__ rdw,
                       const float* __restrict__ rpw, const float* __restrict__ c1w,
                       const float* __restrict__ c2w, const float* __restrict__ fw,
                       float* __restrict__ ws)
{
  u16* wsb = (u16*)(ws + 768);
  const int total = 768 + W_U16_TOTAL;
  for (int idx = blockIdx.x*blockDim.x + threadIdx.x; idx < total; idx += gridDim.x*blockDim.x){
    if (idx < 768){                      // dconv0 fp32: [6][128] <- [128][2][3]
      int k = idx >> 7, o = idx & 127;
      ws[idx] = d0w[o*6 + k];
      continue;
    }
    int e = idx - 768;
    float v;
    if (e < WP_OFF){                     // res dconv frags
      int L = e / WA_PER_L, r = e % WA_PER_L;
      int w = r / 6144, r2 = r % 6144;
      int t = r2 >> 11, r3 = r2 & 2047;  // t stride 2048
      int kb = r3 >> 9, r4 = r3 & 511;
      int l = r4 >> 3, j = r4 & 7;
      int o = w*16 + (l & 15);
      int c = kb*32 + ((l >> 4) << 3) + j;
      v = rdw[((L*128 + o)*128 + c)*3 + t];
    } else if (e < WF_OFF){              // pointwise frags (res0..3, c1, c2)
      int t2 = e - WP_OFF;
      int i = t2 / WP_PER, r = t2 % WP_PER;
      int w = r >> 11, r2 = r & 2047;
      int kb = r2 >> 9, r3 = r2 & 511;
      int l = r3 >> 3, j = r3 & 7;
      int o = w*16 + (l & 15);
      int c = kb*32 + ((l >> 4) << 3) + j;
      v = (i < 4) ? rpw[(i*128 + o)*128 + c]
        : (i == 4) ? c1w[o*128 + c] : c2w[o*128 + c];
    } else {                             // final frags
      int e2 = e - WF_OFF;
      int ot = e2 >> 11, r = e2 & 2047;
      int kb = r >> 9, r2 = r & 511;
      int l = r2 >> 3, j = r2 & 7;
      int o = ot*16 + (l & 15);
      int c = kb*32 + ((l >> 4) << 3) + j;
      v = fw[o*128 + c];
    }
    wsb[e] = f2bf(v);
  }
}

// ---- directional conv 128->128 via MFMA: A(haloed) -> B(compact p' rows) ----
// wave owns ONE o-tile (16 ch) and row-tiles [T0,T1)
__device__ __forceinline__ void dconv_mfma(const u16* __restrict__ As, u16* __restrict__ Bs,
    const u16* __restrict__ wloc, const float* __restrict__ bias,
    int lane, int ot, int T0, int T1, int off0, int off2)
{
  const int col = lane & 15, kg = lane >> 4, koff = kg*8;
  bf16x8 wa[12];
  #pragma unroll
  for (int f=0; f<12; ++f)
    wa[f] = *(const bf16x8*)(wloc + ot*6144 + f*512 + lane*8);
  f32x4 bz = *(const f32x4*)(bias + ot*16 + kg*4);
  const int c1 = (col+1)*ROWP;
  #pragma unroll 1
  for (int tile=T0; tile<T1; ++tile){
    int rb = (tile+1)*RSTRIDE17 + c1;
    const u16* s0 = As + rb + off0 + koff;
    const u16* s1 = As + rb + koff;
    const u16* s2 = As + rb + off2 + koff;
    f32x4 a0 = bz;
    __builtin_amdgcn_s_setprio(1);
    #pragma unroll
    for (int kb=0; kb<4; ++kb){
      bf16x8 v0 = *(const bf16x8*)(s0 + kb*32);
      bf16x8 v1 = *(const bf16x8*)(s1 + kb*32);
      bf16x8 v2 = *(const bf16x8*)(s2 + kb*32);
      a0 = mfma16(wa[kb],   v0, a0);
      a0 = mfma16(wa[4+kb], v1, a0);
      a0 = mfma16(wa[8+kb], v2, a0);
    }
    __builtin_amdgcn_s_setprio(0);
    if (col < 15){
      u16* dp = Bs + (tile*16+col)*ROWP + ot*16 + kg*4;
      uint2 w0; w0.x = packbf(silu_f(a0[0]), silu_f(a0[1]));
      w0.y = packbf(silu_f(a0[2]), silu_f(a0[3]));
      *(uint2*)dp = w0;
    }
  }
}

// ---- pointwise 128->128 via MFMA; wave owns o-tiles {2og2,2og2+1}, tiles [T0,T1) ----
template<bool SRC_HALO, bool DST_HALO, bool RESID>
__device__ __forceinline__ void pw_mfma(const u16* __restrict__ src, u16* __restrict__ dst,
    const u16* __restrict__ wloc, const float* __restrict__ bias,
    int lane, int og2, int T0, int T1)
{
  const int col = lane & 15, kg = lane >> 4, koff = kg*8;
  bf16x8 wp[2][4];
  #pragma unroll
  for (int ot=0; ot<2; ++ot)
    #pragma unroll
    for (int kb=0; kb<4; ++kb)
      wp[ot][kb] = *(const bf16x8*)(wloc + (og2*2+ot)*2048 + kb*512 + lane*8);
  f32x4 bz0 = *(const f32x4*)(bias + og2*32 + kg*4);
  f32x4 bz1 = *(const f32x4*)(bias + og2*32 + 16 + kg*4);
  const int chb = og2*32 + kg*4;
  const int c1 = (col+1)*ROWP;
  #pragma unroll 2
  for (int tile=T0; tile<T1; ++tile){
    int r1 = (tile+1)*17 + col + 1;
    int p2 = tile*16 + col;
    int rsrc = SRC_HALO ? r1*ROWP : p2*ROWP;
    const u16* S = src + rsrc + koff;
    f32x4 a0 = bz0, a1 = bz1;
    __builtin_amdgcn_s_setprio(1);
    #pragma unroll
    for (int kb=0; kb<4; ++kb){
      bf16x8 v = *(const bf16x8*)(S + kb*32);
      a0 = mfma16(wp[0][kb], v, a0);
      a1 = mfma16(wp[1][kb], v, a1);
    }
    __builtin_amdgcn_s_setprio(0);
    if (col < 15){
      int rdst = DST_HALO ? r1*ROWP : p2*ROWP;
      u16* dp = dst + rdst + chb;
      float s0 = silu_f(a0[0]), s1 = silu_f(a0[1]), s2 = silu_f(a0[2]), s3 = silu_f(a0[3]);
      float t0 = silu_f(a1[0]), t1 = silu_f(a1[1]), t2 = silu_f(a1[2]), t3 = silu_f(a1[3]);
      if (RESID){
        uint2 r0 = *(const uint2*)dp;
        uint2 r1v = *(const uint2*)(dp+16);
        s0 += bflo(r0.x); s1 += bfhi(r0.x); s2 += bflo(r0.y); s3 += bfhi(r0.y);
        t0 += bflo(r1v.x); t1 += bfhi(r1v.x); t2 += bflo(r1v.y); t3 += bfhi(r1v.y);
      }
      uint2 w0; w0.x = packbf(s0, s1); w0.y = packbf(s2, s3);
      *(uint2*)dp = w0;
      uint2 w1; w1.x = packbf(t0, t1); w1.y = packbf(t2, t3);
      *(uint2*)(dp+16) = w1;
    }
  }
}

__global__ void __launch_bounds__(1024, 1)
mix9_main(const float* __restrict__ x,
          const float* __restrict__ b_d0,
          const float* __restrict__ b_rd,
          const float* __restrict__ b_rp,
          const float* __restrict__ b_c1,
          const float* __restrict__ b_c2,
          const float* __restrict__ b_fin,
          const float* __restrict__ wt,
          float* __restrict__ out)
{
  extern __shared__ u16 sm[];
  u16* As = sm;              // [289][136] haloed bf16 activations, zero halo
  u16* Bs = sm + A_ELEMS;    // [241][136] compact p'-row scratch

  const int blk  = blockIdx.x;
  const int b    = blk >> 2, d = blk & 3;
  const int tid  = threadIdx.x;
  const int wave = __builtin_amdgcn_readfirstlane(tid >> 6);
  const int lane = tid & 63;

  // dconv split: 8 o-groups (1 o-tile each) x 2 position halves
  const int ogd  = wave >> 1;
  const int phd  = wave & 1;
  const int T0d  = phd * 8;
  const int T1d  = phd ? NT : 8;
  // pw split: 4 o-groups (2 o-tiles each) x 4 position quarters
  const int og2  = wave >> 2;
  const int ph4  = wave & 3;
  const int T0p  = ph4 * 4;
  const int T1p  = (ph4 == 3) ? NT : T0p + 4;
  // dconv0 prologue split: 8 channel groups x 2 position halves
  const int ob   = (wave & 7) * 16;
  const int phal = wave >> 3;

  const int DI0[4] = {0,-1, 1,-1}, DJ0[4] = {-1, 0,-1,-1};
  const int DI2[4] = {0, 1,-1, 1}, DJ2[4] = { 1, 0, 1, 1};
  const int di0 = DI0[d], dj0 = DJ0[d], di2 = DI2[d], dj2 = DJ2[d];
  const int off0 = (di0*17 + dj0)*ROWP;
  const int off2 = (di2*17 + dj2)*ROWP;

  // zero haloed A; stage input image into B-region as fp32
  for (int k2 = tid; k2 < A_ELEMS; k2 += 1024) As[k2] = 0;
  float* xs = (float*)Bs;          // 450 floats
  for (int k2 = tid; k2 < 2*NPOS; k2 += 1024) xs[k2] = x[b*(2*NPOS) + k2];
  __syncthreads();

  // ---- dconv0: 2 -> 128 (tiny K: plain VALU, fp32 weights) -> A ----
  #pragma unroll 1
  for (int pb = 0; pb < 2; ++pb){
    int pp = phal*128 + pb*64 + lane;   // p' = i*16 + j, covers [0,256)
    int i = pp >> 4, j = pp & 15;
    if (i >= 15 || j >= 15) continue;
    float acc[16];
    #pragma unroll
    for (int oo=0;oo<16;++oo) acc[oo] = b_d0[ob+oo];
    #pragma unroll
    for (int c=0;c<2;++c){
      int i0=i+di0, j0=j+dj0, i2=i+di2, j2=j+dj2;
      float x0 = ((unsigned)i0<15u && (unsigned)j0<15u) ? xs[c*NPOS + i0*15 + j0] : 0.f;
      float x1 = xs[c*NPOS + i*15 + j];
      float x2 = ((unsigned)i2<15u && (unsigned)j2<15u) ? xs[c*NPOS + i2*15 + j2] : 0.f;
      const float* w0r = wt + (c*3+0)*128 + ob;
      const float* w1r = wt + (c*3+1)*128 + ob;
      const float* w2r = wt + (c*3+2)*128 + ob;
      #pragma unroll
      for (int oo=0;oo<16;++oo)
        acc[oo] = fmaf(w0r[oo],x0, fmaf(w1r[oo],x1, fmaf(w2r[oo],x2, acc[oo])));
    }
    u16* dp = As + ((i+1)*17 + (j+1))*ROWP + ob;
    #pragma unroll
    for (int oo=0;oo<16;oo+=2)
      *(u32*)(dp+oo) = packbf(silu_f(acc[oo]), silu_f(acc[oo+1]));
  }
  __syncthreads();

  const u16* wsb = (const u16*)(wt + 768);

  // ---- 4 directional res blocks (MFMA) ----
  #pragma unroll 1
  for (int L = 0; L < 4; ++L){
    dconv_mfma(As, Bs, wsb + L*WA_PER_L, b_rd + L*128, lane, ogd, T0d, T1d, off0, off2);
    __syncthreads();
    pw_mfma<false,true,true>(Bs, As, wsb + WP_OFF + L*WP_PER, b_rp + L*128, lane, og2, T0p, T1p);
    __syncthreads();
  }

  // ---- Conv0d res block ----
  pw_mfma<true,false,false>(As, Bs, wsb + WP_OFF + 4*WP_PER, b_c1, lane, og2, T0p, T1p);
  __syncthreads();
  pw_mfma<false,true,true>(Bs, As, wsb + WP_OFF + 5*WP_PER, b_c2, lane, og2, T0p, T1p);
  __syncthreads();

  // ---- final 1x1: 128 -> 64, MFMA, write global fp32 ----
  {
    const int col = lane & 15, kg = lane >> 4, koff = kg*8;
    const int ogf = wave >> 2;          // 4 o-groups of 16 ch
    const int phf = wave & 3;
    const int T0f = phf * 4;
    const int T1f = (phf == 3) ? NT : T0f + 4;
    const u16* wl = wsb + WF_OFF + ogf*2048;
    bf16x8 wf[4];
    #pragma unroll
    for (int kb=0;kb<4;++kb) wf[kb] = *(const bf16x8*)(wl + (kb*64 + lane)*8);
    f32x4 bias4 = *(const f32x4*)(b_fin + ogf*16 + kg*4);
    const int c1 = (col+1)*ROWP;
    #pragma unroll 1
    for (int tile = T0f; tile < T1f; ++tile){
      int rb = (tile+1)*RSTRIDE17 + c1;
      const u16* S = As + rb + koff;
      f32x4 acc = bias4;
      #pragma unroll
      for (int kb=0;kb<4;++kb)
        acc = mfma16(wf[kb], *(const bf16x8*)(S + kb*32), acc);
      if (col < 15){
        float* op = out + ((size_t)((b*4 + d)*64 + ogf*16 + kg*4))*NPOS + tile*15 + col;
        op[0]      = acc[0];
        op[NPOS]   = acc[1];
        op[2*NPOS] = acc[2];
        op[3*NPOS] = acc[3];
      }
    }
  }
}

extern "C" void kernel_launch(void* const* d_in, const int* in_sizes, int n_in,
                              void* d_out, int out_size, void* d_ws, size_t ws_size,
                              hipStream_t stream)
{
  const float* x     = (const float*)d_in[0];
  const float* w_d0  = (const float*)d_in[1];
  const float* b_d0  = (const float*)d_in[2];
  const float* w_rd  = (const float*)d_in[3];
  const float* b_rd  = (const float*)d_in[4];
  const float* w_rp  = (const float*)d_in[5];
  const float* b_rp  = (const float*)d_in[6];
  const float* w_c1  = (const float*)d_in[7];
  const float* b_c1  = (const float*)d_in[8];
  const float* w_c2  = (const float*)d_in[9];
  const float* b_c2  = (const float*)d_in[10];
  const float* w_fin = (const float*)d_in[11];
  const float* b_fin = (const float*)d_in[12];
  float* wt  = (float*)d_ws;
  float* out = (float*)d_out;

  prep_w<<<128, 512, 0, stream>>>(w_d0, w_rd, w_rp, w_c1, w_c2, w_fin, wt);

  (void)hipFuncSetAttribute((const void*)mix9_main,
                            hipFuncAttributeMaxDynamicSharedMemorySize, LDS_BYTES);
  mix9_main<<<1024, 1024, LDS_BYTES, stream>>>(x, b_d0, b_rd, b_rp, b_c1, b_c2, b_fin, wt, out);
}